// Round 1
// 3365.826 us; speedup vs baseline: 1.6425x; 1.6425x over previous
//
#include <hip/hip_runtime.h>
#include <hip/hip_bf16.h>

// RNN scratch model: B=64, T=512, HID=1024, VOCAB=2048.
// Phase 1: persistent 64-WG recurrence (W_hh slice in VGPR B-frags, flag-chained steps).
//          Handoff via write-through (sc0 sc1) stores + LLC-bypass loads: NO wbl2/inv.
// Phase 2: m97-style 128x128 bf16 MFMA GEMM for Y = Hall[1..512] @ W_hq^T(+b_q).

#define BSZ  64
#define TSTEPS 512
#define HID  1024
#define VOC  2048

typedef __attribute__((ext_vector_type(8))) __bf16 bf16x8;
typedef __attribute__((ext_vector_type(4))) float  f32x4;

// ---- workspace layout (bytes) ----
// Hall : bf16 [513][64][1024]  = 67,239,936   (Hall[0]=h0, Hall[t+1]=state after step t)
// Wt   : bf16 [2048][1024]     =  4,194,304   (W_hq transposed, for B-fragment k-contiguity)
// flags: u32  [513][64]        =    131,328
#define HALL_BYTES  67239936ull
#define WT_BYTES     4194304ull
#define FLAGS_BYTES   131328ull

__device__ inline void async_load16(const void* g, void* l) {
    __builtin_amdgcn_global_load_lds(
        (const __attribute__((address_space(1))) void*)g,
        (__attribute__((address_space(3))) void*)l, 16, 0, 0);
}

// 8 x 16B LLC-bypass loads (sc0 sc1), 64B stride, all left in flight (no waitcnt).
__device__ inline void load8_cc(const __hip_bfloat16* base, bf16x8* a) {
    asm volatile(
        "global_load_dwordx4 %0, %8, off sc0 sc1\n\t"
        "global_load_dwordx4 %1, %8, off offset:64 sc0 sc1\n\t"
        "global_load_dwordx4 %2, %8, off offset:128 sc0 sc1\n\t"
        "global_load_dwordx4 %3, %8, off offset:192 sc0 sc1\n\t"
        "global_load_dwordx4 %4, %8, off offset:256 sc0 sc1\n\t"
        "global_load_dwordx4 %5, %8, off offset:320 sc0 sc1\n\t"
        "global_load_dwordx4 %6, %8, off offset:384 sc0 sc1\n\t"
        "global_load_dwordx4 %7, %8, off offset:448 sc0 sc1"
        : "=&v"(a[0]), "=&v"(a[1]), "=&v"(a[2]), "=&v"(a[3]),
          "=&v"(a[4]), "=&v"(a[5]), "=&v"(a[6]), "=&v"(a[7])
        : "v"(base)
        : "memory");
}

// write-through bf16 store: lands at the LLC (device-visible), no cache-maintenance ops
__device__ inline void store_bf16_wt(__hip_bfloat16* p, float v) {
    const __hip_bfloat16 hv = __float2bfloat16(v);
    __hip_atomic_store((unsigned short*)p, __builtin_bit_cast(unsigned short, hv),
                       __ATOMIC_RELAXED, __HIP_MEMORY_SCOPE_SYSTEM);
}

// ---------------- Phase 1: recurrence ----------------
// grid 64 x 256. WG w owns output columns [16w, 16w+16). wave m owns batch rows [16m,16m+16).
// Per step: pre = Hall[t] @ W_hh[:,slice] (MFMA, K=1024) + W_xh[x_t[b], slice] + b_h[slice];
// Hall[t+1] slice = bf16(tanh(pre)).  Cross-WG handoff: write-through data + relaxed flags.
__global__ __launch_bounds__(256, 1) void rnn_phase1(
    const int* __restrict__ X, const float* __restrict__ h0,
    const float* __restrict__ W_xh, const float* __restrict__ W_hh,
    const float* __restrict__ b_h,
    __hip_bfloat16* __restrict__ Hall, float* __restrict__ Hfin,
    unsigned int* __restrict__ flags)
{
    const int wg   = blockIdx.x;       // 0..63 -> j-slice
    const int j0   = wg * 16;
    const int tid  = threadIdx.x;
    const int wave = tid >> 6;
    const int lane = tid & 63;
    const int lrow = lane & 15;        // MFMA row/col lane index
    const int lq   = lane >> 4;        // quad 0..3
    const int row0 = wave * 16;        // batch rows for this wave

    // ---- W_hh slice -> VGPR B-fragments. frag[ks]: B[k=32ks+8lq+j][j0+lrow], j=0..7.
    bf16x8 Bfr[32];
#pragma unroll
    for (int ks = 0; ks < 32; ++ks) {
        const int kb = ks * 32 + lq * 8;
        bf16x8 v;
#pragma unroll
        for (int j = 0; j < 8; ++j)
            v[j] = (__bf16)W_hh[(size_t)(kb + j) * HID + j0 + lrow];
        Bfr[ks] = v;
    }
    const float bh = b_h[j0 + lrow];   // hoisted: lane's column bias

    // ---- publish Hall[0] slice from h0 (write-through so consumers' LLC reads see it)
    for (int i = tid; i < BSZ * 16; i += 256) {
        const int b = i >> 4, c = i & 15;
        store_bf16_wt(Hall + (size_t)b * HID + j0 + c, h0[(size_t)b * HID + j0 + c]);
    }
    asm volatile("s_waitcnt vmcnt(0)" ::: "memory");
    __syncthreads();
    if (tid == 0)
        __hip_atomic_store(&flags[wg], 1u, __ATOMIC_RELAXED, __HIP_MEMORY_SCOPE_SYSTEM);

    for (int t = 0; t < TSTEPS; ++t) {
        // prefetch gather term before the flag wait (X, W_xh are read-only, stay L2-warm)
        float g[4];
#pragma unroll
        for (int r = 0; r < 4; ++r) {
            const int b = row0 + lq * 4 + r;          // C-layout row this lane will own
            const int x = X[b * TSTEPS + t];
            g[r] = W_xh[(size_t)x * HID + j0 + lrow];
        }
        // wait for all 64 producer slices of Hall[t] (lane i watches flag i).
        // Relaxed system-scope loads (sc0 sc1): read the LLC directly, no buffer_inv.
        {
            unsigned int* fl = flags + (size_t)t * 64;
            int guard = 0;
            while (__hip_atomic_load(&fl[lane], __ATOMIC_RELAXED, __HIP_MEMORY_SCOPE_SYSTEM) == 0u) {
                __builtin_amdgcn_s_sleep(1);
                if (++guard > (1 << 17)) break;       // safety: fail loud, don't hang
            }
        }

        const __hip_bfloat16* Arow =
            Hall + (size_t)t * (BSZ * HID) + (size_t)(row0 + lrow) * HID + lq * 8;
        // all 32 fragment loads in flight (LLC-bypass), single drain, then MFMA
        bf16x8 a[32];
        load8_cc(Arow,       a);
        load8_cc(Arow + 256, a + 8);
        load8_cc(Arow + 512, a + 16);
        load8_cc(Arow + 768, a + 24);
        asm volatile("s_waitcnt vmcnt(0)" ::: "memory");
        __builtin_amdgcn_sched_barrier(0);            // rule #18: keep MFMA below the drain

        f32x4 acc0 = {0.f, 0.f, 0.f, 0.f};
        f32x4 acc1 = {0.f, 0.f, 0.f, 0.f};
#pragma unroll
        for (int i = 0; i < 16; ++i) {                // 2 independent dep-chains
            acc0 = __builtin_amdgcn_mfma_f32_16x16x32_bf16(a[2 * i],     Bfr[2 * i],     acc0, 0, 0, 0);
            acc1 = __builtin_amdgcn_mfma_f32_16x16x32_bf16(a[2 * i + 1], Bfr[2 * i + 1], acc1, 0, 0, 0);
        }

        __hip_bfloat16* Hn = Hall + (size_t)(t + 1) * (BSZ * HID);
#pragma unroll
        for (int r = 0; r < 4; ++r) {
            const int b = row0 + lq * 4 + r;
            const float v = tanhf(acc0[r] + acc1[r] + g[r] + bh);
            store_bf16_wt(Hn + (size_t)b * HID + j0 + lrow, v);
            if (t == TSTEPS - 1) Hfin[(size_t)b * HID + j0 + lrow] = v;
        }
        asm volatile("s_waitcnt vmcnt(0)" ::: "memory"); // all this thread's WT stores at LLC
        __syncthreads();                                  // -> whole WG's slice published
        if (tid == 0)                                     // relaxed flag: no wbl2, plain sc0 sc1 store
            __hip_atomic_store(&flags[(size_t)(t + 1) * 64 + wg], 1u,
                               __ATOMIC_RELAXED, __HIP_MEMORY_SCOPE_SYSTEM);
    }
}

// ---------------- W_hq transpose: f32 [1024][2048] -> bf16 [2048][1024] ----------------
__global__ __launch_bounds__(256) void transpose_whq(
    const float* __restrict__ Whq, __hip_bfloat16* __restrict__ Wt)
{
    __shared__ float tile[32][33];
    const int n0 = blockIdx.x * 32, k0 = blockIdx.y * 32;
    const int tx = threadIdx.x & 31, ty = threadIdx.x >> 5;   // 32 x 8
    for (int yy = ty; yy < 32; yy += 8)
        tile[yy][tx] = Whq[(size_t)(k0 + yy) * VOC + n0 + tx];
    __syncthreads();
    for (int yy = ty; yy < 32; yy += 8)
        Wt[(size_t)(n0 + yy) * HID + k0 + tx] = __float2bfloat16(tile[tx][yy]);
}

// ---------------- Phase 2: Y = A @ Wt^T + b_q ----------------
// A bf16 [32768][1024] (= Hall[1..512]), Bt bf16 [2048][1024], Y f32 [32768][2048].
// 128x128 tile, BK=64, global_load_lds(16B) staging with XOR-swizzled 16B slots:
// slot(row,b) = row*8 + (b ^ (row&7))  -> frag ds_read_b128 spread evenly over bank columns.
__global__ __launch_bounds__(256, 2) void gemm_phase2(
    const __hip_bfloat16* __restrict__ A, const __hip_bfloat16* __restrict__ Bt,
    const float* __restrict__ b_q, float* __restrict__ Y)
{
    __shared__ __attribute__((aligned(16))) char As[16384];
    __shared__ __attribute__((aligned(16))) char Bs[16384];
    const int tid  = threadIdx.x;
    const int wave = tid >> 6, lane = tid & 63;
    const int m0 = blockIdx.y * 128, n0 = blockIdx.x * 128;
    const int wm = (wave >> 1) * 64, wn = (wave & 1) * 64;
    const int l15 = lane & 15, lq = lane >> 4;
    const int rsub = lane >> 3;                    // 0..7: row-within-8 for staging
    const int bb   = (lane & 7) ^ (rsub & 7);      // logical k-block this lane fetches

    f32x4 acc[4][4] = {};

    for (int kt = 0; kt < 16; ++kt) {
        __syncthreads();                           // readers of previous tile done
#pragma unroll
        for (int i = 0; i < 4; ++i) {
            const int ii = wave * 4 + i;           // staging instruction id 0..15
            const size_t koff = (size_t)kt * 64 + bb * 8;
            async_load16(A  + (size_t)(m0 + ii * 8 + rsub) * HID + koff, As + ii * 1024);
            async_load16(Bt + (size_t)(n0 + ii * 8 + rsub) * HID + koff, Bs + ii * 1024);
        }
        __syncthreads();                           // vmcnt drained -> LDS tiles ready
#pragma unroll
        for (int ks = 0; ks < 2; ++ks) {
            bf16x8 af[4], bf[4];
#pragma unroll
            for (int mi = 0; mi < 4; ++mi) {
                const int row  = wm + mi * 16 + l15;
                const int slot = row * 8 + ((ks * 4 + lq) ^ (row & 7));
                af[mi] = *(const bf16x8*)(As + slot * 16);
            }
#pragma unroll
            for (int ni = 0; ni < 4; ++ni) {
                const int row  = wn + ni * 16 + l15;
                const int slot = row * 8 + ((ks * 4 + lq) ^ (row & 7));
                bf[ni] = *(const bf16x8*)(Bs + slot * 16);
            }
#pragma unroll
            for (int mi = 0; mi < 4; ++mi)
#pragma unroll
                for (int ni = 0; ni < 4; ++ni)
                    acc[mi][ni] = __builtin_amdgcn_mfma_f32_16x16x32_bf16(
                        af[mi], bf[ni], acc[mi][ni], 0, 0, 0);
        }
    }

    float bqv[4];
#pragma unroll
    for (int ni = 0; ni < 4; ++ni) bqv[ni] = b_q[n0 + wn + ni * 16 + l15];
#pragma unroll
    for (int mi = 0; mi < 4; ++mi)
#pragma unroll
        for (int r = 0; r < 4; ++r) {
            const int row = m0 + wm + mi * 16 + lq * 4 + r;
            float* yr = Y + (size_t)row * VOC + n0 + wn + l15;
#pragma unroll
            for (int ni = 0; ni < 4; ++ni)
                yr[ni * 16] = acc[mi][ni][r] + bqv[ni];
        }
}

extern "C" void kernel_launch(void* const* d_in, const int* in_sizes, int n_in,
                              void* d_out, int out_size, void* d_ws, size_t ws_size,
                              hipStream_t stream) {
    const int*   X    = (const int*)  d_in[0];   // [64][512] int32
    const float* h0   = (const float*)d_in[1];   // [64][1024]
    const float* W_xh = (const float*)d_in[2];   // [2048][1024]
    const float* W_hh = (const float*)d_in[3];   // [1024][1024]
    const float* b_h  = (const float*)d_in[4];   // [1024]
    const float* W_hq = (const float*)d_in[5];   // [1024][2048]
    const float* b_q  = (const float*)d_in[6];   // [2048]

    float* Y    = (float*)d_out;                 // [512*64][2048]
    float* Hfin = Y + (size_t)TSTEPS * BSZ * VOC;// [64][1024]

    char* ws = (char*)d_ws;                      // needs ~68.3 MB
    __hip_bfloat16* Hall  = (__hip_bfloat16*)ws;
    __hip_bfloat16* Wt    = (__hip_bfloat16*)(ws + HALL_BYTES);
    unsigned int*   flags = (unsigned int*)(ws + HALL_BYTES + WT_BYTES);

    hipMemsetAsync(flags, 0, FLAGS_BYTES, stream);
    transpose_whq<<<dim3(VOC / 32, HID / 32), 256, 0, stream>>>(W_hq, Wt);
    rnn_phase1<<<64, 256, 0, stream>>>(X, h0, W_xh, W_hh, b_h, Hall, Hfin, flags);
    gemm_phase2<<<dim3(VOC / 128, (TSTEPS * BSZ) / 128), 256, 0, stream>>>(
        Hall + (size_t)BSZ * HID, Wt, b_q, Y);
}